// Round 1
// baseline (2076.391 us; speedup 1.0000x reference)
//
#include <hip/hip_runtime.h>
#include <hip/hip_bf16.h>

typedef __attribute__((ext_vector_type(8))) short short8;
typedef __attribute__((ext_vector_type(4))) float f32x4;

#define HW_GRID (256 * 512)

__device__ __forceinline__ unsigned short f2bf(float f) {
  union { float f; unsigned int u; } v; v.f = f;
  unsigned int u = v.u;
  u += 0x7FFFu + ((u >> 16) & 1u);   // round-to-nearest-even
  return (unsigned short)(u >> 16);
}
__device__ __forceinline__ float bf2f(unsigned short b) {
  union { unsigned int u; float f; } v; v.u = ((unsigned int)b) << 16;
  return v.f;
}

// MFMA B-fragment layout for 16x16x32: B[k][j] lives at lane=((k%32)/8)*16 + j%16, elem=k%8
__device__ __forceinline__ int frag_off(int k, int j, int nf) {
  int kstep = k >> 5, ke = k & 31;
  int lane = ((ke >> 3) << 4) | (j & 15);
  int e = ke & 7;
  int nfrag = j >> 4;
  return (((kstep * nf + nfrag) << 6) + lane) * 8 + e;
}

__global__ void prep_weights(const float* __restrict__ w1, const float* __restrict__ w2,
                             const float* __restrict__ w3, unsigned short* __restrict__ ws) {
  int idx = blockIdx.x * 256 + threadIdx.x;
  if (idx < 65536) {               // w_pos1: K=256 (padded from 231) x N=256
    int k = idx >> 8, j = idx & 255;
    float v = (k < 231) ? w1[k * 256 + j] : 0.0f;
    ws[frag_off(k, j, 16)] = f2bf(v);
  }
  if (idx < 131072) {              // w_pos2: K=256 x N=512
    int k = idx >> 9, j = idx & 511;
    ws[65536 + frag_off(k, j, 32)] = f2bf(w2[k * 512 + j]);
  }
  if (idx < 196608) {              // w_pred1: K=768 x N=256
    int k = idx >> 8, j = idx & 255;
    ws[196608 + frag_off(k, j, 16)] = f2bf(w3[k * 256 + j]);
  }
}

// XOR-swizzled LDS index (ushort units). Kills 32-way bank conflict on
// stride-512B/1536B row-major ds_read_b128 (Guideline 4 / T2).
__device__ __forceinline__ int swz(int row, int col, int rowhalfs) {
  int byte = (col << 1) ^ ((row & 7) << 4);
  return row * rowhalfs + (byte >> 1);
}

// A-tile (64 x K, bf16, swizzled LDS) @ B (frag-order in ws) -> acc[4][NW]
template<int KSTEPS, int NW, int AROWH>
__device__ __forceinline__ void gemm_mfma(const unsigned short* __restrict__ At,
                                          const short8* __restrict__ Bf,
                                          int nftot, int nf0, int lane,
                                          f32x4 acc[4][NW]) {
  const int arow = lane & 15;
  const int acol = (lane >> 4) << 3;
  for (int ks = 0; ks < KSTEPS; ++ks) {
    short8 a[4];
#pragma unroll
    for (int m = 0; m < 4; ++m)
      a[m] = *reinterpret_cast<const short8*>(&At[swz(m * 16 + arow, ks * 32 + acol, AROWH)]);
#pragma unroll
    for (int n = 0; n < NW; ++n) {
      short8 b = Bf[(ks * nftot + nf0 + n) * 64 + lane];
#pragma unroll
      for (int m = 0; m < 4; ++m)
        acc[m][n] = __builtin_amdgcn_mfma_f32_16x16x32_bf16(a[m], b, acc[m][n], 0, 0, 0);
    }
  }
}

// C layout: col = lane&15, row = (lane>>4)*4 + reg  [measured m89/m91]
template<int NW, bool RELU>
__device__ __forceinline__ void epilogue(f32x4 acc[4][NW], const float* __restrict__ bias,
                                         int bcol0, unsigned short* __restrict__ dst,
                                         int dcol0, int drowh, int lane) {
  const int jlo = lane & 15;
  const int rhi = (lane >> 4) << 2;
#pragma unroll
  for (int n = 0; n < NW; ++n) {
    float bv = bias[bcol0 + n * 16 + jlo];
#pragma unroll
    for (int m = 0; m < 4; ++m) {
#pragma unroll
      for (int t = 0; t < 4; ++t) {
        float v = acc[m][n][t] + bv;
        if (RELU) v = fmaxf(v, 0.0f);
        dst[swz(m * 16 + rhi + t, dcol0 + n * 16 + jlo, drowh)] = f2bf(v);
      }
    }
  }
}

__global__ __launch_bounds__(512) void fused_decoder(
    const float* __restrict__ grid, const float* __restrict__ sgrad,
    const float* __restrict__ qpos, const float* __restrict__ quinf,
    const float* __restrict__ qsdf, const float* __restrict__ qnrm,
    const float* __restrict__ qflow,
    const float* __restrict__ b1, const float* __restrict__ b2,
    const float* __restrict__ b3, const float* __restrict__ w4,
    const float* __restrict__ b4,
    const unsigned short* __restrict__ wsh,
    float* __restrict__ out, int N) {
  // ctx (64x768 bf16, 96KB); first 512B/row region doubles as ff (64x256) earlier in time
  __shared__ __align__(16) unsigned short ctx_lds[64 * 768];
  __shared__ __align__(16) unsigned short h_lds[64 * 256];  // h, then h2
  __shared__ int qx0[64], qx1[64], qy0[64], qy1[64];
  __shared__ float qw[4][64];
  __shared__ float id_lds[64][12];

  const int tid = threadIdx.x;
  const int lane = tid & 63;
  const int wid = tid >> 6;
  const int row0 = blockIdx.x << 6;

  // ---- Phase 0a: per-row coords, sdf-grad gather, identity (threads 0..63)
  if (tid < 64) {
    const int r = tid;
    int g = row0 + r; if (g >= N) g = N - 1;
    float px = qpos[g * 2], py = qpos[g * 2 + 1];
    float xn = 2.0f * (px - (-2.0f)) / 6.0f - 1.0f;
    float yn = 2.0f * (py - (-1.5f)) / 3.0f - 1.0f;
    xn = fminf(fmaxf(xn, -1.0f), 1.0f);
    yn = fminf(fmaxf(yn, -1.0f), 1.0f);
    float ix = (xn + 1.0f) * 0.5f * 511.0f;
    float iy = (yn + 1.0f) * 0.5f * 255.0f;
    float x0f = floorf(ix), y0f = floorf(iy);
    float wx = ix - x0f, wy = iy - y0f;
    int x0 = (int)fminf(fmaxf(x0f, 0.0f), 511.0f);
    int x1 = (int)fminf(fmaxf(x0f + 1.0f, 0.0f), 511.0f);
    int y0 = (int)fminf(fmaxf(y0f, 0.0f), 255.0f);
    int y1 = (int)fminf(fmaxf(y0f + 1.0f, 0.0f), 255.0f);
    qx0[r] = x0; qx1[r] = x1; qy0[r] = y0; qy1[r] = y1;
    float w00 = (1.0f - wx) * (1.0f - wy), w01 = wx * (1.0f - wy);
    float w10 = (1.0f - wx) * wy,          w11 = wx * wy;
    qw[0][r] = w00; qw[1][r] = w01; qw[2][r] = w10; qw[3][r] = w11;
    int o00 = y0 * 512 + x0, o01 = y0 * 512 + x1, o10 = y1 * 512 + x0, o11 = y1 * 512 + x1;
    float sg0 = w00 * sgrad[o00] + w01 * sgrad[o01] + w10 * sgrad[o10] + w11 * sgrad[o11];
    const float* s1 = sgrad + HW_GRID;
    float sg1 = w00 * s1[o00] + w01 * s1[o01] + w10 * s1[o10] + w11 * s1[o11];
    float idv[11] = {px, py, quinf[g * 2], quinf[g * 2 + 1], qsdf[g], sg0, sg1,
                     qnrm[g * 2], qnrm[g * 2 + 1], qflow[g * 2], qflow[g * 2 + 1]};
#pragma unroll
    for (int i = 0; i < 11; ++i) {
      id_lds[r][i] = idv[i];
      ctx_lds[swz(r, i, 256)] = f2bf(idv[i]);      // ff identity cols
    }
    for (int c = 231; c < 256; ++c) ctx_lds[swz(r, c, 256)] = 0;  // K-pad
  }
  __syncthreads();

  // ---- Phase 0b: fourier sin/cos, 64 rows x 110 pairs, all 512 threads
  for (int e = tid; e < 7040; e += 512) {
    int r = e / 110, rem = e % 110;
    int i = rem / 10, k = rem % 10;
    float fr = 3.14159265358979323846f * (float)(1 << k);  // exact pow2 scale of f32(pi)
    float arg = id_lds[r][i] * fr;
    float s, c;
    sincosf(arg, &s, &c);
    ctx_lds[swz(r, 11 + i * 10 + k, 256)] = f2bf(s);
    ctx_lds[swz(r, 121 + i * 10 + k, 256)] = f2bf(c);
  }
  __syncthreads();

  // ---- Phase 1: h = relu(ff @ w_pos1 + b1)   (M=64,K=256pad,N=256; wave: 32 cols)
  {
    f32x4 acc[4][2] = {};
    gemm_mfma<8, 2, 256>(ctx_lds, (const short8*)wsh, 16, wid * 2, lane, acc);
    epilogue<2, true>(acc, b1, wid * 32, h_lds, wid * 32, 256, lane);
  }
  __syncthreads();

  // ---- Phase 2a: gather local_geo -> ctx[:,0:256] (overwrites dead ff region)
  {
    const int r = tid >> 3;
    const int c0 = (tid & 7) << 5;
    int o00 = qy0[r] * 512 + qx0[r], o01 = qy0[r] * 512 + qx1[r];
    int o10 = qy1[r] * 512 + qx0[r], o11 = qy1[r] * 512 + qx1[r];
    float w00 = qw[0][r], w01 = qw[1][r], w10 = qw[2][r], w11 = qw[3][r];
    const float* gp = grid + (size_t)c0 * HW_GRID;
#pragma unroll 4
    for (int cc = 0; cc < 32; ++cc, gp += HW_GRID) {
      float v = w00 * gp[o00] + w01 * gp[o01] + w10 * gp[o10] + w11 * gp[o11];
      ctx_lds[swz(r, c0 + cc, 768)] = f2bf(v);
    }
  }
  // ---- Phase 2b: pos_enc = h @ w_pos2 + b2 -> ctx[:,256:768] (disjoint LDS, no barrier)
  {
    f32x4 acc[4][4] = {};
    gemm_mfma<8, 4, 256>(h_lds, (const short8*)(wsh + 65536), 32, wid * 4, lane, acc);
    epilogue<4, false>(acc, b2, wid * 64, ctx_lds, 256 + wid * 64, 768, lane);
  }
  __syncthreads();

  // ---- Phase 3: h2 = relu(ctx @ w_pred1 + b3)  (K=768)
  {
    f32x4 acc[4][2] = {};
    gemm_mfma<24, 2, 768>(ctx_lds, (const short8*)(wsh + 196608), 16, wid * 2, lane, acc);
    epilogue<2, true>(acc, b3, wid * 32, h_lds, wid * 32, 256, lane);
  }
  __syncthreads();

  // ---- Phase 4: out = h2 @ w_pred2 + b4  (N=4, per-thread dot)
  if (tid < 256) {
    const int r = tid >> 2, j = tid & 3;
    float sum = b4[j];
#pragma unroll 8
    for (int k = 0; k < 256; ++k)
      sum += bf2f(h_lds[swz(r, k, 256)]) * w4[k * 4 + j];
    int g = row0 + r;
    if (g < N) out[g * 4 + j] = sum;
  }
}

extern "C" void kernel_launch(void* const* d_in, const int* in_sizes, int n_in,
                              void* d_out, int out_size, void* d_ws, size_t ws_size,
                              hipStream_t stream) {
  const float* grid  = (const float*)d_in[0];
  const float* sgrad = (const float*)d_in[1];
  const float* qpos  = (const float*)d_in[2];
  const float* quinf = (const float*)d_in[3];
  const float* qsdf  = (const float*)d_in[4];
  const float* qnrm  = (const float*)d_in[5];
  const float* qflow = (const float*)d_in[6];
  const float* w1 = (const float*)d_in[7];
  const float* b1 = (const float*)d_in[8];
  const float* w2 = (const float*)d_in[9];
  const float* b2 = (const float*)d_in[10];
  const float* w3 = (const float*)d_in[11];
  const float* b3 = (const float*)d_in[12];
  const float* w4 = (const float*)d_in[13];
  const float* b4 = (const float*)d_in[14];
  float* out = (float*)d_out;
  unsigned short* wsh = (unsigned short*)d_ws;

  const int N = in_sizes[2] / 2;  // 200000

  prep_weights<<<768, 256, 0, stream>>>(w1, w2, w3, wsh);
  fused_decoder<<<(N + 63) / 64, 512, 0, stream>>>(
      grid, sgrad, qpos, quinf, qsdf, qnrm, qflow,
      b1, b2, b3, w4, b4, wsh, out, N);
}

// Round 2
// 482.545 us; speedup vs baseline: 4.3030x; 4.3030x over previous
//
#include <hip/hip_runtime.h>
#include <hip/hip_bf16.h>

typedef __attribute__((ext_vector_type(8))) short short8;
typedef __attribute__((ext_vector_type(4))) float f32x4;

#define HW_GRID (256 * 512)
#define WS_WEIGHTS_USHORTS 393216        // 786 KB of bf16 weight fragments
#define WS_GRID_USHORTS (HW_GRID * 256)  // 67 MB bf16 HWC grid

__device__ __forceinline__ unsigned short f2bf(float f) {
  union { float f; unsigned int u; } v; v.f = f;
  unsigned int u = v.u;
  u += 0x7FFFu + ((u >> 16) & 1u);   // round-to-nearest-even
  return (unsigned short)(u >> 16);
}
__device__ __forceinline__ float bf2f(unsigned short b) {
  union { unsigned int u; float f; } v; v.u = ((unsigned int)b) << 16;
  return v.f;
}

// MFMA B-fragment layout for 16x16x32: B[k][j] lives at lane=((k%32)/8)*16 + j%16, elem=k%8
__device__ __forceinline__ int frag_off(int k, int j, int nf) {
  int kstep = k >> 5, ke = k & 31;
  int lane = ((ke >> 3) << 4) | (j & 15);
  int e = ke & 7;
  int nfrag = j >> 4;
  return (((kstep * nf + nfrag) << 6) + lane) * 8 + e;
}

__global__ void prep_weights(const float* __restrict__ w1, const float* __restrict__ w2,
                             const float* __restrict__ w3, unsigned short* __restrict__ ws) {
  int idx = blockIdx.x * 256 + threadIdx.x;
  if (idx < 65536) {               // w_pos1: K=256 (padded from 231) x N=256
    int k = idx >> 8, j = idx & 255;
    float v = (k < 231) ? w1[k * 256 + j] : 0.0f;
    ws[frag_off(k, j, 16)] = f2bf(v);
  }
  if (idx < 131072) {              // w_pos2: K=256 x N=512
    int k = idx >> 9, j = idx & 511;
    ws[65536 + frag_off(k, j, 32)] = f2bf(w2[k * 512 + j]);
  }
  if (idx < 196608) {              // w_pred1: K=768 x N=256
    int k = idx >> 8, j = idx & 255;
    ws[196608 + frag_off(k, j, 16)] = f2bf(w3[k * 256 + j]);
  }
}

// CHW fp32 -> HWC bf16 transpose. Block: 256 thr, 32 consecutive pixels x 256 ch.
__global__ __launch_bounds__(256) void prep_grid(const float* __restrict__ grid,
                                                 unsigned short* __restrict__ gh) {
  __shared__ unsigned short t_lds[32][264];   // +8 pad: spreads LDS banks on read
  const int pix0 = blockIdx.x * 32;
  const int xl = threadIdx.x & 31;            // pixel within block
  const int cg = threadIdx.x >> 5;            // 8 channel groups
#pragma unroll 8
  for (int cc = 0; cc < 32; ++cc) {
    int c = cg * 32 + cc;
    t_lds[xl][c] = f2bf(grid[(size_t)c * HW_GRID + pix0 + xl]);  // coalesced along x
  }
  __syncthreads();
  const int p = threadIdx.x >> 3;             // pixel
  const int s = threadIdx.x & 7;              // 32-ch slice
  unsigned short* dst = gh + ((size_t)(pix0 + p)) * 256 + s * 32;
  const unsigned short* src = &t_lds[p][s * 32];
#pragma unroll
  for (int u = 0; u < 4; ++u)
    *reinterpret_cast<short8*>(dst + u * 8) =
        *reinterpret_cast<const short8*>(src + u * 8);           // coalesced along c
}

// XOR-swizzled LDS index (ushort units). Kills 32-way bank conflict on
// stride-512B/1536B row-major ds_read_b128 (Guideline 4 / T2).
__device__ __forceinline__ int swz(int row, int col, int rowhalfs) {
  int byte = (col << 1) ^ ((row & 7) << 4);
  return row * rowhalfs + (byte >> 1);
}

// A-tile (64 x K, bf16, swizzled LDS) @ B (frag-order in ws) -> acc[4][NW]
template<int KSTEPS, int NW, int AROWH>
__device__ __forceinline__ void gemm_mfma(const unsigned short* __restrict__ At,
                                          const short8* __restrict__ Bf,
                                          int nftot, int nf0, int lane,
                                          f32x4 acc[4][NW]) {
  const int arow = lane & 15;
  const int acol = (lane >> 4) << 3;
  for (int ks = 0; ks < KSTEPS; ++ks) {
    short8 a[4];
#pragma unroll
    for (int m = 0; m < 4; ++m)
      a[m] = *reinterpret_cast<const short8*>(&At[swz(m * 16 + arow, ks * 32 + acol, AROWH)]);
#pragma unroll
    for (int n = 0; n < NW; ++n) {
      short8 b = Bf[(ks * nftot + nf0 + n) * 64 + lane];
#pragma unroll
      for (int m = 0; m < 4; ++m)
        acc[m][n] = __builtin_amdgcn_mfma_f32_16x16x32_bf16(a[m], b, acc[m][n], 0, 0, 0);
    }
  }
}

// C layout: col = lane&15, row = (lane>>4)*4 + reg  [measured m89/m91]
template<int NW, bool RELU>
__device__ __forceinline__ void epilogue(f32x4 acc[4][NW], const float* __restrict__ bias,
                                         int bcol0, unsigned short* __restrict__ dst,
                                         int dcol0, int drowh, int lane) {
  const int jlo = lane & 15;
  const int rhi = (lane >> 4) << 2;
#pragma unroll
  for (int n = 0; n < NW; ++n) {
    float bv = bias[bcol0 + n * 16 + jlo];
#pragma unroll
    for (int m = 0; m < 4; ++m) {
#pragma unroll
      for (int t = 0; t < 4; ++t) {
        float v = acc[m][n][t] + bv;
        if (RELU) v = fmaxf(v, 0.0f);
        dst[swz(m * 16 + rhi + t, dcol0 + n * 16 + jlo, drowh)] = f2bf(v);
      }
    }
  }
}

template<bool HWC>
__global__ __launch_bounds__(512) void fused_decoder(
    const float* __restrict__ grid, const float* __restrict__ sgrad,
    const float* __restrict__ qpos, const float* __restrict__ quinf,
    const float* __restrict__ qsdf, const float* __restrict__ qnrm,
    const float* __restrict__ qflow,
    const float* __restrict__ b1, const float* __restrict__ b2,
    const float* __restrict__ b3, const float* __restrict__ w4,
    const float* __restrict__ b4,
    const unsigned short* __restrict__ wsh,
    float* __restrict__ out, int N) {
  // ctx (64x768 bf16, 96KB); first 512B/row region doubles as ff (64x256) earlier in time
  __shared__ __align__(16) unsigned short ctx_lds[64 * 768];
  __shared__ __align__(16) unsigned short h_lds[64 * 256];  // h, then h2
  __shared__ int qo00[64], qo01[64], qo10[64], qo11[64];
  __shared__ float qw[4][64];
  __shared__ float id_lds[64][12];

  const int tid = threadIdx.x;
  const int lane = tid & 63;
  const int wid = tid >> 6;
  const int row0 = blockIdx.x << 6;

  // ---- Phase 0a: per-row coords, sdf-grad gather, identity (threads 0..63)
  if (tid < 64) {
    const int r = tid;
    int g = row0 + r; if (g >= N) g = N - 1;
    float px = qpos[g * 2], py = qpos[g * 2 + 1];
    float xn = 2.0f * (px - (-2.0f)) / 6.0f - 1.0f;
    float yn = 2.0f * (py - (-1.5f)) / 3.0f - 1.0f;
    xn = fminf(fmaxf(xn, -1.0f), 1.0f);
    yn = fminf(fmaxf(yn, -1.0f), 1.0f);
    float ix = (xn + 1.0f) * 0.5f * 511.0f;
    float iy = (yn + 1.0f) * 0.5f * 255.0f;
    float x0f = floorf(ix), y0f = floorf(iy);
    float wx = ix - x0f, wy = iy - y0f;
    int x0 = (int)fminf(fmaxf(x0f, 0.0f), 511.0f);
    int x1 = (int)fminf(fmaxf(x0f + 1.0f, 0.0f), 511.0f);
    int y0 = (int)fminf(fmaxf(y0f, 0.0f), 255.0f);
    int y1 = (int)fminf(fmaxf(y0f + 1.0f, 0.0f), 255.0f);
    int o00 = y0 * 512 + x0, o01 = y0 * 512 + x1, o10 = y1 * 512 + x0, o11 = y1 * 512 + x1;
    qo00[r] = o00; qo01[r] = o01; qo10[r] = o10; qo11[r] = o11;
    float w00 = (1.0f - wx) * (1.0f - wy), w01 = wx * (1.0f - wy);
    float w10 = (1.0f - wx) * wy,          w11 = wx * wy;
    qw[0][r] = w00; qw[1][r] = w01; qw[2][r] = w10; qw[3][r] = w11;
    float sg0 = w00 * sgrad[o00] + w01 * sgrad[o01] + w10 * sgrad[o10] + w11 * sgrad[o11];
    const float* s1 = sgrad + HW_GRID;
    float sg1 = w00 * s1[o00] + w01 * s1[o01] + w10 * s1[o10] + w11 * s1[o11];
    float idv[11] = {px, py, quinf[g * 2], quinf[g * 2 + 1], qsdf[g], sg0, sg1,
                     qnrm[g * 2], qnrm[g * 2 + 1], qflow[g * 2], qflow[g * 2 + 1]};
#pragma unroll
    for (int i = 0; i < 11; ++i) {
      id_lds[r][i] = idv[i];
      ctx_lds[swz(r, i, 256)] = f2bf(idv[i]);      // ff identity cols
    }
    for (int c = 231; c < 256; ++c) ctx_lds[swz(r, c, 256)] = 0;  // K-pad
  }
  __syncthreads();

  // ---- Phase 0b: fourier sin/cos, 64 rows x 110 pairs, all 512 threads
  for (int e = tid; e < 7040; e += 512) {
    int r = e / 110, rem = e % 110;
    int i = rem / 10, k = rem % 10;
    float fr = 3.14159265358979323846f * (float)(1 << k);  // exact pow2 scale of f32(pi)
    float arg = id_lds[r][i] * fr;
    float s, c;
    sincosf(arg, &s, &c);
    ctx_lds[swz(r, 11 + i * 10 + k, 256)] = f2bf(s);
    ctx_lds[swz(r, 121 + i * 10 + k, 256)] = f2bf(c);
  }
  __syncthreads();

  // ---- Phase 1: h = relu(ff @ w_pos1 + b1)   (M=64,K=256pad,N=256; wave: 32 cols)
  {
    f32x4 acc[4][2] = {};
    gemm_mfma<8, 2, 256>(ctx_lds, (const short8*)wsh, 16, wid * 2, lane, acc);
    epilogue<2, true>(acc, b1, wid * 32, h_lds, wid * 32, 256, lane);
  }
  __syncthreads();

  // ---- Phase 2a: gather local_geo -> ctx[:,0:256] (overwrites dead ff region)
  if (HWC) {
    // HWC bf16 grid in workspace: each corner is a contiguous 512B run of 256 ch.
    const int r = tid >> 3;
    const int s = tid & 7;           // 32-channel slice
    const unsigned short* gh = wsh + WS_WEIGHTS_USHORTS;
    const unsigned short* g00 = gh + (size_t)qo00[r] * 256 + s * 32;
    const unsigned short* g01 = gh + (size_t)qo01[r] * 256 + s * 32;
    const unsigned short* g10 = gh + (size_t)qo10[r] * 256 + s * 32;
    const unsigned short* g11 = gh + (size_t)qo11[r] * 256 + s * 32;
    float w00 = qw[0][r], w01 = qw[1][r], w10 = qw[2][r], w11 = qw[3][r];
#pragma unroll
    for (int u = 0; u < 4; ++u) {    // 8 channels per iteration
      short8 a = *reinterpret_cast<const short8*>(g00 + u * 8);
      short8 b = *reinterpret_cast<const short8*>(g01 + u * 8);
      short8 c = *reinterpret_cast<const short8*>(g10 + u * 8);
      short8 d = *reinterpret_cast<const short8*>(g11 + u * 8);
      short8 res;
#pragma unroll
      for (int i = 0; i < 8; ++i) {
        float v = w00 * bf2f((unsigned short)a[i]) + w01 * bf2f((unsigned short)b[i]) +
                  w10 * bf2f((unsigned short)c[i]) + w11 * bf2f((unsigned short)d[i]);
        res[i] = (short)f2bf(v);
      }
      *reinterpret_cast<short8*>(&ctx_lds[swz(r, s * 32 + u * 8, 768)]) = res;
    }
  } else {
    // Fallback: CHW fp32 gather straight from the input grid.
    const int r = tid >> 3;
    const int c0 = (tid & 7) << 5;
    int o00 = qo00[r], o01 = qo01[r], o10 = qo10[r], o11 = qo11[r];
    float w00 = qw[0][r], w01 = qw[1][r], w10 = qw[2][r], w11 = qw[3][r];
    const float* gp = grid + (size_t)c0 * HW_GRID;
#pragma unroll 4
    for (int cc = 0; cc < 32; ++cc, gp += HW_GRID) {
      float v = w00 * gp[o00] + w01 * gp[o01] + w10 * gp[o10] + w11 * gp[o11];
      ctx_lds[swz(r, c0 + cc, 768)] = f2bf(v);
    }
  }
  // ---- Phase 2b: pos_enc = h @ w_pos2 + b2 -> ctx[:,256:768] (disjoint LDS, no barrier)
  {
    f32x4 acc[4][4] = {};
    gemm_mfma<8, 4, 256>(h_lds, (const short8*)(wsh + 65536), 32, wid * 4, lane, acc);
    epilogue<4, false>(acc, b2, wid * 64, ctx_lds, 256 + wid * 64, 768, lane);
  }
  __syncthreads();

  // ---- Phase 3: h2 = relu(ctx @ w_pred1 + b3)  (K=768)
  {
    f32x4 acc[4][2] = {};
    gemm_mfma<24, 2, 768>(ctx_lds, (const short8*)(wsh + 196608), 16, wid * 2, lane, acc);
    epilogue<2, true>(acc, b3, wid * 32, h_lds, wid * 32, 256, lane);
  }
  __syncthreads();

  // ---- Phase 4: out = h2 @ w_pred2 + b4  (N=4, per-thread dot)
  if (tid < 256) {
    const int r = tid >> 2, j = tid & 3;
    float sum = b4[j];
#pragma unroll 8
    for (int k = 0; k < 256; ++k)
      sum += bf2f(h_lds[swz(r, k, 256)]) * w4[k * 4 + j];
    int g = row0 + r;
    if (g < N) out[g * 4 + j] = sum;
  }
}

extern "C" void kernel_launch(void* const* d_in, const int* in_sizes, int n_in,
                              void* d_out, int out_size, void* d_ws, size_t ws_size,
                              hipStream_t stream) {
  const float* grid  = (const float*)d_in[0];
  const float* sgrad = (const float*)d_in[1];
  const float* qpos  = (const float*)d_in[2];
  const float* quinf = (const float*)d_in[3];
  const float* qsdf  = (const float*)d_in[4];
  const float* qnrm  = (const float*)d_in[5];
  const float* qflow = (const float*)d_in[6];
  const float* w1 = (const float*)d_in[7];
  const float* b1 = (const float*)d_in[8];
  const float* w2 = (const float*)d_in[9];
  const float* b2 = (const float*)d_in[10];
  const float* w3 = (const float*)d_in[11];
  const float* b3 = (const float*)d_in[12];
  const float* w4 = (const float*)d_in[13];
  const float* b4 = (const float*)d_in[14];
  float* out = (float*)d_out;
  unsigned short* wsh = (unsigned short*)d_ws;

  const int N = in_sizes[2] / 2;  // 200000
  const bool hwc = ws_size >= (size_t)(WS_WEIGHTS_USHORTS + WS_GRID_USHORTS) * 2;

  prep_weights<<<768, 256, 0, stream>>>(w1, w2, w3, wsh);
  if (hwc) {
    prep_grid<<<HW_GRID / 32, 256, 0, stream>>>(grid, wsh + WS_WEIGHTS_USHORTS);
    fused_decoder<true><<<(N + 63) / 64, 512, 0, stream>>>(
        grid, sgrad, qpos, quinf, qsdf, qnrm, qflow,
        b1, b2, b3, w4, b4, wsh, out, N);
  } else {
    fused_decoder<false><<<(N + 63) / 64, 512, 0, stream>>>(
        grid, sgrad, qpos, quinf, qsdf, qnrm, qflow,
        b1, b2, b3, w4, b4, wsh, out, N);
  }
}